// Round 3
// baseline (759.808 us; speedup 1.0000x reference)
//
#include <hip/hip_runtime.h>
#include <hip/hip_bf16.h>

typedef __attribute__((ext_vector_type(8))) short bf16x8;
typedef __attribute__((ext_vector_type(4))) float f32x4;

#define T_SEQ   512
#define B_BATCH 128
#define H_DIM   64
#define MB      64               // rows (t*B+b) per block
#define XS_STRIDE 132            // f32 per row of x chunk (128 + 4 pad, keeps 16B row align)
#define ZS_STRIDE 193            // f32 per row of z tile (192 + 1 pad)
#define HS_STRIDE 68             // f32 per row of h tile (64 + 4 pad)
#define LASTROW ((T_SEQ - 1) * B_BATCH)   // 65408

// accurate sigmoid (libm expf, ~1 ulp)
__device__ __forceinline__ float acc_sigmoid(float x) {
    return 1.0f / (1.0f + expf(-x));
}

// 3-term bf16 split: f ~= hi + mid + lo with residual ~2^-25 rel.
// Each subtraction is exact (Sterbenz: hi within half-ulp of f).
__device__ __forceinline__ void split3_8(const float* p, bf16x8& hi, bf16x8& mid, bf16x8& lo) {
    float4 a = *(const float4*)p;
    float4 b = *(const float4*)(p + 4);
    float v[8] = {a.x, a.y, a.z, a.w, b.x, b.y, b.z, b.w};
#pragma unroll
    for (int i = 0; i < 8; ++i) {
        float f = v[i];
        unsigned short h = __builtin_bit_cast(unsigned short, __float2bfloat16(f));
        float hf = __builtin_bit_cast(float, (unsigned)h << 16);
        float r1 = f - hf;
        unsigned short m = __builtin_bit_cast(unsigned short, __float2bfloat16(r1));
        float mf = __builtin_bit_cast(float, (unsigned)m << 16);
        float r2 = r1 - mf;
        unsigned short l = __builtin_bit_cast(unsigned short, __float2bfloat16(r2));
        hi[i]  = (short)h;
        mid[i] = (short)m;
        lo[i]  = (short)l;
    }
}

// 6-product accumulate: (h1+m1+l1)(h2+m2+l2), dropping m*l, l*m, l*l (~2^-26)
__device__ __forceinline__ f32x4 mfma6(bf16x8 ah, bf16x8 am, bf16x8 al,
                                       bf16x8 bh, bf16x8 bm, bf16x8 bl, f32x4 c) {
    c = __builtin_amdgcn_mfma_f32_16x16x32_bf16(ah, bh, c, 0, 0, 0);
    c = __builtin_amdgcn_mfma_f32_16x16x32_bf16(ah, bm, c, 0, 0, 0);
    c = __builtin_amdgcn_mfma_f32_16x16x32_bf16(am, bh, c, 0, 0, 0);
    c = __builtin_amdgcn_mfma_f32_16x16x32_bf16(ah, bl, c, 0, 0, 0);
    c = __builtin_amdgcn_mfma_f32_16x16x32_bf16(al, bh, c, 0, 0, 0);
    c = __builtin_amdgcn_mfma_f32_16x16x32_bf16(am, bm, c, 0, 0, 0);
    return c;
}

// LDS layout (total 68352 B, 2 blocks/CU):
//   [0, 49408)      union: xsf [64][132] f32 (33792 B) | zs [64][193] f32 (49408 B)
//   [49408, 66816)  hs  [64][68] f32  (layer-0 LN output)
//   [66816, 67584)  bt0 [192] f32   (b0+th0, gates 1..3)
//   [67584, 68352)  bt1 [192] f32
__global__ __launch_bounds__(256) void qlstm_fused(
    const float* __restrict__ x,
    const float* __restrict__ W0,
    const float* __restrict__ b0,
    const float* __restrict__ th0,
    const float* __restrict__ g0,
    const float* __restrict__ be0,
    const float* __restrict__ W1,
    const float* __restrict__ b1,
    const float* __restrict__ th1,
    const float* __restrict__ g1,
    const float* __restrict__ be1,
    float* __restrict__ out)
{
    __shared__ __align__(16) char lds[68352];
    float* xsf = (float*)lds;                     // [64][132]
    float* zs  = (float*)lds;                     // [64][193] (aliases xsf)
    float* hs  = (float*)(lds + 49408);           // [64][68]
    float* bt0 = (float*)(lds + 66816);           // [192]
    float* bt1 = (float*)(lds + 67584);           // [192]

    const int tid = threadIdx.x;
    const long rowbase = (long)blockIdx.x * MB;

    float* out0 = out;                                      // h1      [T*B][64]
    float* out1 = out + (long)T_SEQ * B_BATCH * H_DIM;      // h0[-1]  [128][64]
    float* out2 = out1 + B_BATCH * H_DIM;                   // c0[-1]
    float* out3 = out2 + B_BATCH * H_DIM;                   // h1[-1]
    float* out4 = out3 + B_BATCH * H_DIM;                   // c1[-1]

    // stage combined bias + theta for gates 1..3 (flat row in (4,64) = 64 + gc)
    if (tid < 192) {
        bt0[tid] = b0[64 + tid] + th0[64 + tid];
        bt1[tid] = b1[64 + tid] + th1[64 + tid];
    }

    const int lane = tid & 63;
    const int wave = tid >> 6;
    const int ln   = lane & 15;   // MFMA m/n lane index
    const int quad = lane >> 4;   // MFMA k-group / row-group
    const int cw   = wave * 48;   // this wave's N-column base (192 cols / 4 waves)

    // W0 row pointers: z-col gc -> flat row gc+64 (gates 1..3), row stride 576
    const float* wrow[3];
    for (int nt = 0; nt < 3; ++nt) {
        int gc = cw + nt * 16 + ln;
        wrow[nt] = W0 + (size_t)(gc + 64) * 576;
    }

    // ------- GEMM1: z0[64][192] = x[64][512] . W0g^T, 3-term split, K chunks of 128
    f32x4 acc[4][3];
    for (int mt = 0; mt < 4; ++mt)
        for (int nt = 0; nt < 3; ++nt)
            acc[mt][nt] = (f32x4){0.f, 0.f, 0.f, 0.f};

    for (int kc = 0; kc < 512; kc += 128) {
        {   // stage x chunk [64][128] f32 -> xsf (float4, coalesced)
            int c8 = tid & 31;       // float4 col 0..31
            int r0 = tid >> 5;       // 0..7
            for (int it = 0; it < 8; ++it) {
                int r = r0 + it * 8;
                float4 v = *(const float4*)(x + (rowbase + r) * 512 + kc + c8 * 4);
                *(float4*)(xsf + r * XS_STRIDE + c8 * 4) = v;
            }
        }
        __syncthreads();
        for (int k0 = 0; k0 < 128; k0 += 32) {
            int ka = k0 + quad * 8;
            bf16x8 ah[4], am[4], al[4];
            for (int mt = 0; mt < 4; ++mt)
                split3_8(xsf + (mt * 16 + ln) * XS_STRIDE + ka, ah[mt], am[mt], al[mt]);
            for (int nt = 0; nt < 3; ++nt) {
                bf16x8 bh, bm, bl;
                split3_8(wrow[nt] + kc + ka, bh, bm, bl);
                for (int mt = 0; mt < 4; ++mt)
                    acc[mt][nt] = mfma6(ah[mt], am[mt], al[mt], bh, bm, bl, acc[mt][nt]);
            }
        }
        __syncthreads();   // xsf reads done before next stage / zs overwrite
    }

    // epilogue: D[m][n]: col = lane&15, row = quad*4 + reg  [measured m89/m91]
    for (int mt = 0; mt < 4; ++mt)
        for (int nt = 0; nt < 3; ++nt)
            for (int i = 0; i < 4; ++i) {
                int row = mt * 16 + quad * 4 + i;
                int col = cw + nt * 16 + ln;
                zs[row * ZS_STRIDE + col] = acc[mt][nt][i];
            }
    __syncthreads();

    // ------- cumprod(cos(z + b + th)) layer 0 (wave-uniform branch: wave 3 idles)
    if (tid < 192) {
        int gi = tid >> 6;
        int r  = tid & 63;
        float* zrow = zs + r * ZS_STRIDE + gi * 64;
        const float* btg = bt0 + gi * 64;
        float p = 1.0f;
        for (int n = 0; n < 64; ++n) {
            p *= cosf(zrow[n] + btg[n]);   // accurate libm cos
            zrow[n] = p;
        }
    }
    __syncthreads();

    // ------- gates + two-pass LayerNorm layer 0 -> hs (+ last-t outputs out1/out2)
    {
        int r = tid >> 2;            // row 0..63
        int j = tid & 3;             // 16-element chunk
        long tbrow = rowbase + r;
        bool lastt = (tbrow >= LASTROW);
        int bidx = (int)(tbrow - LASTROW);
        const float* zr = zs + r * ZS_STRIDE;
        float h[16];
        float s = 0.f;
        for (int i = 0; i < 16; ++i) {
            int n = j * 16 + i;
            float q1 = zr[n];            // gate 1 (input)
            float q2 = zr[64 + n];       // gate 2 (update)
            float q3 = zr[128 + n];      // gate 3 (output)
            float ig = acc_sigmoid(q1);
            float gg = tanhf(acc_sigmoid(q2));
            float og = acc_sigmoid(q3);
            float c  = ig * gg;
            float hv = og * tanhf(c);
            h[i] = hv;
            s += hv;
            if (lastt) out2[bidx * 64 + n] = c;
        }
        s += __shfl_xor(s, 1);  s += __shfl_xor(s, 2);
        float mu = s * (1.0f / 64.0f);
        float s2 = 0.f;
        for (int i = 0; i < 16; ++i) {           // two-pass: matches mean((h-mu)^2)
            float d = h[i] - mu;
            s2 += d * d;
        }
        s2 += __shfl_xor(s2, 1); s2 += __shfl_xor(s2, 2);
        float var = s2 * (1.0f / 64.0f);
        float rs  = rsqrtf(var + 1e-5f);
        for (int i = 0; i < 16; ++i) {
            int n = j * 16 + i;
            float hl = (h[i] - mu) * rs * g0[n] + be0[n];
            hs[r * HS_STRIDE + n] = hl;
            if (lastt) out1[bidx * 64 + n] = hl;
        }
    }
    __syncthreads();

    // ------- GEMM2: z1[64][192] = h0[64][64] . W1g^T, 3-term split, K=64
    f32x4 acc2[4][3];
    for (int mt = 0; mt < 4; ++mt)
        for (int nt = 0; nt < 3; ++nt)
            acc2[mt][nt] = (f32x4){0.f, 0.f, 0.f, 0.f};
    const float* wrow1[3];
    for (int nt = 0; nt < 3; ++nt) {
        int gc = cw + nt * 16 + ln;
        wrow1[nt] = W1 + (size_t)(gc + 64) * 128;   // row stride H+H=128, only k<64 used
    }
    for (int k0 = 0; k0 < 64; k0 += 32) {
        int ka = k0 + quad * 8;
        bf16x8 ah[4], am[4], al[4];
        for (int mt = 0; mt < 4; ++mt)
            split3_8(hs + (mt * 16 + ln) * HS_STRIDE + ka, ah[mt], am[mt], al[mt]);
        for (int nt = 0; nt < 3; ++nt) {
            bf16x8 bh, bm, bl;
            split3_8(wrow1[nt] + ka, bh, bm, bl);
            for (int mt = 0; mt < 4; ++mt)
                acc2[mt][nt] = mfma6(ah[mt], am[mt], al[mt], bh, bm, bl, acc2[mt][nt]);
        }
    }
    // old zs fully consumed before the post-LN0 barrier -> safe to overwrite
    for (int mt = 0; mt < 4; ++mt)
        for (int nt = 0; nt < 3; ++nt)
            for (int i = 0; i < 4; ++i) {
                int row = mt * 16 + quad * 4 + i;
                int col = cw + nt * 16 + ln;
                zs[row * ZS_STRIDE + col] = acc2[mt][nt][i];
            }
    __syncthreads();

    // ------- cumprod layer 1
    if (tid < 192) {
        int gi = tid >> 6;
        int r  = tid & 63;
        float* zrow = zs + r * ZS_STRIDE + gi * 64;
        const float* btg = bt1 + gi * 64;
        float p = 1.0f;
        for (int n = 0; n < 64; ++n) {
            p *= cosf(zrow[n] + btg[n]);
            zrow[n] = p;
        }
    }
    __syncthreads();

    // ------- gates + two-pass LayerNorm layer 1 -> out0 directly (+ out3/out4)
    {
        int r = tid >> 2;
        int j = tid & 3;
        long tbrow = rowbase + r;
        bool lastt = (tbrow >= LASTROW);
        int bidx = (int)(tbrow - LASTROW);
        const float* zr = zs + r * ZS_STRIDE;
        float h[16];
        float s = 0.f;
        for (int i = 0; i < 16; ++i) {
            int n = j * 16 + i;
            float q1 = zr[n];
            float q2 = zr[64 + n];
            float q3 = zr[128 + n];
            float ig = acc_sigmoid(q1);
            float gg = tanhf(acc_sigmoid(q2));
            float og = acc_sigmoid(q3);
            float c  = ig * gg;
            float hv = og * tanhf(c);
            h[i] = hv;
            s += hv;
            if (lastt) out4[bidx * 64 + n] = c;
        }
        s += __shfl_xor(s, 1);  s += __shfl_xor(s, 2);
        float mu = s * (1.0f / 64.0f);
        float s2 = 0.f;
        for (int i = 0; i < 16; ++i) {
            float d = h[i] - mu;
            s2 += d * d;
        }
        s2 += __shfl_xor(s2, 1); s2 += __shfl_xor(s2, 2);
        float var = s2 * (1.0f / 64.0f);
        float rs  = rsqrtf(var + 1e-5f);
        float o4[16];
        for (int i = 0; i < 16; ++i)
            o4[i] = (h[i] - mu) * rs * g1[j * 16 + i] + be1[j * 16 + i];
        float* dst = out0 + tbrow * 64 + j * 16;
        for (int i4 = 0; i4 < 4; ++i4)
            *(float4*)(dst + i4 * 4) = *(float4*)(o4 + i4 * 4);
        if (lastt) {
            float* dst3 = out3 + (long)bidx * 64 + j * 16;
            for (int i4 = 0; i4 < 4; ++i4)
                *(float4*)(dst3 + i4 * 4) = *(float4*)(o4 + i4 * 4);
        }
    }
}

extern "C" void kernel_launch(void* const* d_in, const int* in_sizes, int n_in,
                              void* d_out, int out_size, void* d_ws, size_t ws_size,
                              hipStream_t stream) {
    const float* x   = (const float*)d_in[0];
    const float* W0  = (const float*)d_in[1];
    const float* b0  = (const float*)d_in[2];
    const float* th0 = (const float*)d_in[3];
    const float* g0  = (const float*)d_in[4];
    const float* be0 = (const float*)d_in[5];
    const float* W1  = (const float*)d_in[6];
    const float* b1  = (const float*)d_in[7];
    const float* th1 = (const float*)d_in[8];
    const float* g1  = (const float*)d_in[9];
    const float* be1 = (const float*)d_in[10];

    qlstm_fused<<<dim3(1024), dim3(256), 0, stream>>>(
        x, W0, b0, th0, g0, be0, W1, b1, th1, g1, be1, (float*)d_out);
}

// Round 4
// 328.675 us; speedup vs baseline: 2.3117x; 2.3117x over previous
//
#include <hip/hip_runtime.h>
#include <hip/hip_bf16.h>

typedef __attribute__((ext_vector_type(8))) short bf16x8;
typedef __attribute__((ext_vector_type(4))) float f32x4;

#define T_SEQ   512
#define B_BATCH 128
#define H_DIM   64
#define MB      64               // rows (t*B+b) per block
#define AS_STRIDE 136            // bf16 per row of A split-plane (128 + 8 pad; 272B, 16B-mult)
#define ZS_STRIDE 193            // f32 per row of z tile (192 + 1 pad)
#define HS_STRIDE 68             // f32 per row of h tile (64 + 4 pad, 272B rows)
#define LASTROW ((T_SEQ - 1) * B_BATCH)   // 65408

// ws layout (shorts): W0 gate-rows (192x512) planes h/m/l, then W1 (192x64) h/m/l
#define W0H 0
#define W0M 98304
#define W0L 196608
#define W1H 294912
#define W1M 307200
#define W1L 319488
// total 331776 shorts = 663552 bytes of d_ws

// truncation 3-way split: f = h + m + l + r, |r| <= ~2^-24 |f|; subtractions exact
__device__ __forceinline__ void tsplit(float f, unsigned& h, unsigned& m, unsigned& l) {
    unsigned uf = __builtin_bit_cast(unsigned, f);
    h = uf >> 16;
    float hf = __builtin_bit_cast(float, uf & 0xFFFF0000u);
    float r1 = f - hf;
    unsigned u1 = __builtin_bit_cast(unsigned, r1);
    m = u1 >> 16;
    float mf = __builtin_bit_cast(float, u1 & 0xFFFF0000u);
    float r2 = r1 - mf;
    l = __builtin_bit_cast(unsigned, r2) >> 16;
}

// split two floats, pack into one dword per plane (elem0 low, elem1 high)
__device__ __forceinline__ void tsplit2(float a, float b,
                                        unsigned& ph, unsigned& pm, unsigned& pl) {
    unsigned ha, ma, la, hb, mb, lb;
    tsplit(a, ha, ma, la);
    tsplit(b, hb, mb, lb);
    ph = ha | (hb << 16);
    pm = ma | (mb << 16);
    pl = la | (lb << 16);
}

// 6-product accumulate: (h1+m1+l1)(h2+m2+l2), dropping ml, lm, ll (~2^-24 |ab|)
__device__ __forceinline__ f32x4 mfma6(bf16x8 ah, bf16x8 am, bf16x8 al,
                                       bf16x8 bh, bf16x8 bm, bf16x8 bl, f32x4 c) {
    c = __builtin_amdgcn_mfma_f32_16x16x32_bf16(ah, bh, c, 0, 0, 0);
    c = __builtin_amdgcn_mfma_f32_16x16x32_bf16(ah, bm, c, 0, 0, 0);
    c = __builtin_amdgcn_mfma_f32_16x16x32_bf16(am, bh, c, 0, 0, 0);
    c = __builtin_amdgcn_mfma_f32_16x16x32_bf16(ah, bl, c, 0, 0, 0);
    c = __builtin_amdgcn_mfma_f32_16x16x32_bf16(al, bh, c, 0, 0, 0);
    c = __builtin_amdgcn_mfma_f32_16x16x32_bf16(am, bm, c, 0, 0, 0);
    return c;
}

// accurate sigmoid: libm expf + rcp with one Newton step (~0.5 ulp on the divide)
__device__ __forceinline__ float acc_sigmoid(float x) {
    float e = expf(-x);
    float d = 1.0f + e;
    float r = __builtin_amdgcn_rcpf(d);
    r = r * (2.0f - d * r);
    return r;
}

// ---------- kernel 1: pre-split weights into d_ws (runs every launch; ~5 us) ----------
__global__ __launch_bounds__(256) void presplit_w(const float* __restrict__ W0,
                                                  const float* __restrict__ W1,
                                                  short* __restrict__ ws) {
    int i = blockIdx.x * 256 + threadIdx.x;
    if (i < 98304) {                      // W0 gates 1..3: flat rows 64..255, stride 576
        int r = i >> 9, k = i & 511;
        unsigned h, m, l;
        tsplit(W0[(r + 64) * 576 + k], h, m, l);
        ws[W0H + i] = (short)h;
        ws[W0M + i] = (short)m;
        ws[W0L + i] = (short)l;
    } else if (i < 110592) {              // W1 gates 1..3: rows 64..255, stride 128, k<64
        int j = i - 98304;
        int r = j >> 6, k = j & 63;
        unsigned h, m, l;
        tsplit(W1[(r + 64) * 128 + k], h, m, l);
        ws[W1H + j] = (short)h;
        ws[W1M + j] = (short)m;
        ws[W1L + j] = (short)l;
    }
}

// ---------- kernel 2: fused QLSTM ----------
// LDS layout (total 71168 B, 2 blocks/CU):
//   [0, 52224)      union: A split-planes ah/am/al [64][136] bf16 (3 x 17408 B)
//                          | zs [64][193] f32 (49408 B)
//   [52224, 69632)  hs  [64][68] f32  (layer-0 LN output)
//   [69632, 70400)  bt0 [192] f32   (b0+th0, gates 1..3)
//   [70400, 71168)  bt1 [192] f32
__global__ __launch_bounds__(256) void qlstm_fused(
    const float* __restrict__ x,
    const float* __restrict__ b0,
    const float* __restrict__ th0,
    const float* __restrict__ g0,
    const float* __restrict__ be0,
    const float* __restrict__ b1,
    const float* __restrict__ th1,
    const float* __restrict__ g1,
    const float* __restrict__ be1,
    const short* __restrict__ wsp,      // pre-split weight planes
    float* __restrict__ out)
{
    __shared__ __align__(16) char lds[71168];
    short* ah = (short*)lds;                      // [64][136]
    short* am = ah + 64 * AS_STRIDE;
    short* al = am + 64 * AS_STRIDE;
    float* zs  = (float*)lds;                     // [64][193] (aliases planes)
    float* hs  = (float*)(lds + 52224);           // [64][68]
    float* bt0 = (float*)(lds + 69632);           // [192]
    float* bt1 = bt0 + 192;                       // [192]

    const int tid = threadIdx.x;
    const long rowbase = (long)blockIdx.x * MB;

    float* out0 = out;                                      // h1      [T*B][64]
    float* out1 = out + (long)T_SEQ * B_BATCH * H_DIM;      // h0[-1]  [128][64]
    float* out2 = out1 + B_BATCH * H_DIM;                   // c0[-1]
    float* out3 = out2 + B_BATCH * H_DIM;                   // h1[-1]
    float* out4 = out3 + B_BATCH * H_DIM;                   // c1[-1]

    // stage combined bias + theta for gates 1..3 (flat row in (4,64) = 64 + gc)
    if (tid < 192) {
        bt0[tid] = b0[64 + tid] + th0[64 + tid];
        bt1[tid] = b1[64 + tid] + th1[64 + tid];
    }

    const int lane = tid & 63;
    const int wave = tid >> 6;
    const int ln   = lane & 15;   // MFMA m/n lane index
    const int quad = lane >> 4;   // MFMA k-group / row-group
    const int cw   = wave * 48;   // this wave's N-column base (192 cols / 4 waves)

    // B plane row offsets (in shorts) for this wave's 3 column-tiles
    int brow0[3], brow1[3];
    for (int nt = 0; nt < 3; ++nt) {
        int gc = cw + nt * 16 + ln;
        brow0[nt] = gc * 512;
        brow1[nt] = gc * 64;
    }

    // ------- GEMM1: z0[64][192] = x[64][512] . W0g^T, pre-split planes, K chunks of 128
    f32x4 acc[4][3];
    for (int mt = 0; mt < 4; ++mt)
        for (int nt = 0; nt < 3; ++nt)
            acc[mt][nt] = (f32x4){0.f, 0.f, 0.f, 0.f};

    for (int kc = 0; kc < 512; kc += 128) {
        // stage + split x chunk [64][128] -> 3 bf16 planes (each element split ONCE)
        for (int pass = 0; pass < 4; ++pass) {
            int e  = pass * 256 + tid;      // 0..1023 covers 1024*8 = 8192 elements
            int r  = e >> 4;                // row 0..63
            int k8 = (e & 15) << 3;         // col 0,8,...,120
            const float* xp = x + (rowbase + r) * 512 + kc + k8;
            float4 f0 = *(const float4*)xp;
            float4 f1 = *(const float4*)(xp + 4);
            uint4 Ph, Pm, Pl;
            tsplit2(f0.x, f0.y, Ph.x, Pm.x, Pl.x);
            tsplit2(f0.z, f0.w, Ph.y, Pm.y, Pl.y);
            tsplit2(f1.x, f1.y, Ph.z, Pm.z, Pl.z);
            tsplit2(f1.z, f1.w, Ph.w, Pm.w, Pl.w);
            int ao = r * AS_STRIDE + k8;
            *(uint4*)(ah + ao) = Ph;
            *(uint4*)(am + ao) = Pm;
            *(uint4*)(al + ao) = Pl;
        }
        __syncthreads();
        for (int k0 = 0; k0 < 128; k0 += 32) {
            int ka = k0 + quad * 8;
            bf16x8 Ah[4], Am[4], Al[4];
            for (int mt = 0; mt < 4; ++mt) {
                int ao = (mt * 16 + ln) * AS_STRIDE + ka;
                Ah[mt] = *(const bf16x8*)(ah + ao);
                Am[mt] = *(const bf16x8*)(am + ao);
                Al[mt] = *(const bf16x8*)(al + ao);
            }
            for (int nt = 0; nt < 3; ++nt) {
                int bo = brow0[nt] + kc + ka;
                bf16x8 Bh = *(const bf16x8*)(wsp + W0H + bo);
                bf16x8 Bm = *(const bf16x8*)(wsp + W0M + bo);
                bf16x8 Bl = *(const bf16x8*)(wsp + W0L + bo);
                for (int mt = 0; mt < 4; ++mt)
                    acc[mt][nt] = mfma6(Ah[mt], Am[mt], Al[mt], Bh, Bm, Bl, acc[mt][nt]);
            }
        }
        __syncthreads();   // plane reads done before next stage / zs overwrite
    }

    // epilogue: D[m][n]: col = lane&15, row = quad*4 + reg  [measured m89/m91]
    for (int mt = 0; mt < 4; ++mt)
        for (int nt = 0; nt < 3; ++nt)
            for (int i = 0; i < 4; ++i) {
                int row = mt * 16 + quad * 4 + i;
                int col = cw + nt * 16 + ln;
                zs[row * ZS_STRIDE + col] = acc[mt][nt][i];
            }
    __syncthreads();

    // ------- cumprod(cos(z + b + th)) layer 0 (wave-uniform: wave 3 idles)
    if (tid < 192) {
        int gi = tid >> 6;
        int r  = tid & 63;
        float* zrow = zs + r * ZS_STRIDE + gi * 64;
        const float* btg = bt0 + gi * 64;
        float p = 1.0f;
        for (int n = 0; n < 64; ++n) {
            p *= cosf(zrow[n] + btg[n]);   // accurate libm cos
            zrow[n] = p;
        }
    }
    __syncthreads();

    // ------- gates + two-pass LayerNorm layer 0 -> hs (+ last-t outputs out1/out2)
    {
        int r = tid >> 2;            // row 0..63
        int j = tid & 3;             // 16-element chunk
        long tbrow = rowbase + r;
        bool lastt = (tbrow >= LASTROW);
        int bidx = (int)(tbrow - LASTROW);
        const float* zr = zs + r * ZS_STRIDE;
        float h[16];
        float s = 0.f;
        for (int i = 0; i < 16; ++i) {
            int n = j * 16 + i;
            float q1 = zr[n];            // gate 1 (input)
            float q2 = zr[64 + n];       // gate 2 (update)
            float q3 = zr[128 + n];      // gate 3 (output)
            float ig = acc_sigmoid(q1);
            float gg = tanhf(acc_sigmoid(q2));
            float og = acc_sigmoid(q3);
            float c  = ig * gg;
            float hv = og * tanhf(c);
            h[i] = hv;
            s += hv;
            if (lastt) out2[bidx * 64 + n] = c;
        }
        s += __shfl_xor(s, 1);  s += __shfl_xor(s, 2);
        float mu = s * (1.0f / 64.0f);
        float s2 = 0.f;
        for (int i = 0; i < 16; ++i) {           // two-pass: matches mean((h-mu)^2)
            float d = h[i] - mu;
            s2 += d * d;
        }
        s2 += __shfl_xor(s2, 1); s2 += __shfl_xor(s2, 2);
        float var = s2 * (1.0f / 64.0f);
        float rs  = rsqrtf(var + 1e-5f);
        for (int i = 0; i < 16; ++i) {
            int n = j * 16 + i;
            float hl = (h[i] - mu) * rs * g0[n] + be0[n];
            hs[r * HS_STRIDE + n] = hl;
            if (lastt) out1[bidx * 64 + n] = hl;
        }
    }
    __syncthreads();

    // ------- GEMM2: z1[64][192] = h0[64][64] . W1g^T, inline A-split (small), K=64
    f32x4 acc2[4][3];
    for (int mt = 0; mt < 4; ++mt)
        for (int nt = 0; nt < 3; ++nt)
            acc2[mt][nt] = (f32x4){0.f, 0.f, 0.f, 0.f};
    for (int k0 = 0; k0 < 64; k0 += 32) {
        int ka = k0 + quad * 8;
        bf16x8 Ah[4], Am[4], Al[4];
        for (int mt = 0; mt < 4; ++mt) {
            const float* p = hs + (mt * 16 + ln) * HS_STRIDE + ka;
            float4 f0 = *(const float4*)p;
            float4 f1 = *(const float4*)(p + 4);
            uint4 Ph, Pm, Pl;
            tsplit2(f0.x, f0.y, Ph.x, Pm.x, Pl.x);
            tsplit2(f0.z, f0.w, Ph.y, Pm.y, Pl.y);
            tsplit2(f1.x, f1.y, Ph.z, Pm.z, Pl.z);
            tsplit2(f1.z, f1.w, Ph.w, Pm.w, Pl.w);
            Ah[mt] = __builtin_bit_cast(bf16x8, Ph);
            Am[mt] = __builtin_bit_cast(bf16x8, Pm);
            Al[mt] = __builtin_bit_cast(bf16x8, Pl);
        }
        for (int nt = 0; nt < 3; ++nt) {
            int bo = brow1[nt] + ka;
            bf16x8 Bh = *(const bf16x8*)(wsp + W1H + bo);
            bf16x8 Bm = *(const bf16x8*)(wsp + W1M + bo);
            bf16x8 Bl = *(const bf16x8*)(wsp + W1L + bo);
            for (int mt = 0; mt < 4; ++mt)
                acc2[mt][nt] = mfma6(Ah[mt], Am[mt], Al[mt], Bh, Bm, Bl, acc2[mt][nt]);
        }
    }
    // zs region (A-planes) is dead; hs still live but disjoint -> safe to write zs
    for (int mt = 0; mt < 4; ++mt)
        for (int nt = 0; nt < 3; ++nt)
            for (int i = 0; i < 4; ++i) {
                int row = mt * 16 + quad * 4 + i;
                int col = cw + nt * 16 + ln;
                zs[row * ZS_STRIDE + col] = acc2[mt][nt][i];
            }
    __syncthreads();

    // ------- cumprod layer 1
    if (tid < 192) {
        int gi = tid >> 6;
        int r  = tid & 63;
        float* zrow = zs + r * ZS_STRIDE + gi * 64;
        const float* btg = bt1 + gi * 64;
        float p = 1.0f;
        for (int n = 0; n < 64; ++n) {
            p *= cosf(zrow[n] + btg[n]);
            zrow[n] = p;
        }
    }
    __syncthreads();

    // ------- gates + two-pass LayerNorm layer 1 -> out0 directly (+ out3/out4)
    {
        int r = tid >> 2;
        int j = tid & 3;
        long tbrow = rowbase + r;
        bool lastt = (tbrow >= LASTROW);
        int bidx = (int)(tbrow - LASTROW);
        const float* zr = zs + r * ZS_STRIDE;
        float h[16];
        float s = 0.f;
        for (int i = 0; i < 16; ++i) {
            int n = j * 16 + i;
            float q1 = zr[n];
            float q2 = zr[64 + n];
            float q3 = zr[128 + n];
            float ig = acc_sigmoid(q1);
            float gg = tanhf(acc_sigmoid(q2));
            float og = acc_sigmoid(q3);
            float c  = ig * gg;
            float hv = og * tanhf(c);
            h[i] = hv;
            s += hv;
            if (lastt) out4[bidx * 64 + n] = c;
        }
        s += __shfl_xor(s, 1);  s += __shfl_xor(s, 2);
        float mu = s * (1.0f / 64.0f);
        float s2 = 0.f;
        for (int i = 0; i < 16; ++i) {
            float d = h[i] - mu;
            s2 += d * d;
        }
        s2 += __shfl_xor(s2, 1); s2 += __shfl_xor(s2, 2);
        float var = s2 * (1.0f / 64.0f);
        float rs  = rsqrtf(var + 1e-5f);
        float o4[16];
        for (int i = 0; i < 16; ++i)
            o4[i] = (h[i] - mu) * rs * g1[j * 16 + i] + be1[j * 16 + i];
        float* dst = out0 + tbrow * 64 + j * 16;
        for (int i4 = 0; i4 < 4; ++i4)
            *(float4*)(dst + i4 * 4) = *(float4*)(o4 + i4 * 4);
        if (lastt) {
            float* dst3 = out3 + (long)bidx * 64 + j * 16;
            for (int i4 = 0; i4 < 4; ++i4)
                *(float4*)(dst3 + i4 * 4) = *(float4*)(o4 + i4 * 4);
        }
    }
}

extern "C" void kernel_launch(void* const* d_in, const int* in_sizes, int n_in,
                              void* d_out, int out_size, void* d_ws, size_t ws_size,
                              hipStream_t stream) {
    const float* x   = (const float*)d_in[0];
    const float* W0  = (const float*)d_in[1];
    const float* b0  = (const float*)d_in[2];
    const float* th0 = (const float*)d_in[3];
    const float* g0  = (const float*)d_in[4];
    const float* be0 = (const float*)d_in[5];
    const float* W1  = (const float*)d_in[6];
    const float* b1  = (const float*)d_in[7];
    const float* th1 = (const float*)d_in[8];
    const float* g1  = (const float*)d_in[9];
    const float* be1 = (const float*)d_in[10];
    short* wsp = (short*)d_ws;     // needs 663552 B

    presplit_w<<<dim3(432), dim3(256), 0, stream>>>(W0, W1, wsp);
    qlstm_fused<<<dim3(1024), dim3(256), 0, stream>>>(
        x, b0, th0, g0, be0, b1, th1, g1, be1, wsp, (float*)d_out);
}